// Round 1
// 1812.491 us; speedup vs baseline: 1.0316x; 1.0316x over previous
//
#include <hip/hip_runtime.h>
#include <stdint.h>

typedef __attribute__((ext_vector_type(8))) short short8;
typedef __attribute__((ext_vector_type(4))) float floatx4;

#define B_SZ 4096
#define M1 57344        // B*14
#define M2 114688
#define NCAT 1536

// ---- workspace layout (bytes); aliased regions have disjoint lifetimes ----
#define OFF_XB    ((size_t)0)          // x bf16 [57344][1024]; later outcat [114688][512]
#define OFF_BCAT  ((size_t)117440512)  // [1536][1024] bf16  (fc_w | gcn1_w, transposed)
#define OFF_W2T   ((size_t)120586240)  // [1024][512] bf16   (gcn2_w transposed)
#define OFF_T     ((size_t)121634816)  // t1 [57344][512] bf16, then t2 [114688][1024] bf16
#define OFF_ADJN  ((size_t)356515840)  // [2][14][14] f32 normalized adj1/adj2
#define OFF_ADJC  ((size_t)356517888)  // [4096][196] f32 normalized corr-adj
#define OFF_PART1 ((size_t)359729152)  // [56][4096] f32 BN partials branch1
#define OFF_PART2 ((size_t)360646656)  // [56][4096] f32 BN partials branch2
#define OFF_SS1   ((size_t)361564160)  // [56] f32 scale/shift
#define OFF_SS2   ((size_t)361564416)  // [56] f32

__device__ __forceinline__ unsigned short f2bf(float f){
  union { float f; uint32_t u; } v; v.f = f;
  uint32_t r = (v.u + 0x7FFFu + ((v.u >> 16) & 1u)) >> 16;
  return (unsigned short)r;
}
__device__ __forceinline__ float bf2f(unsigned short s){
  union { uint32_t u; float f; } v; v.u = ((uint32_t)s) << 16; return v.f;
}
__device__ __forceinline__ float leaky(float y){ return y >= 0.0f ? y : 0.2f*y; }
__device__ __forceinline__ void gl2lds16(const void* g, void* l){
  __builtin_amdgcn_global_load_lds(
      (const __attribute__((address_space(1))) unsigned int*)g,
      (__attribute__((address_space(3))) unsigned int*)l, 16, 0, 0);
}

// ---- normalize adj1/adj2 (DenseGCNConv sym-norm) -------------------------
__global__ void k_prep_adj(const float* __restrict__ adj1, const float* __restrict__ adj2,
                           float* __restrict__ adjn){
  __shared__ float a[392];
  __shared__ float d[28];
  int tid = threadIdx.x;
  for (int e = tid; e < 392; e += 256){
    int t = e / 196, ij = e % 196, i = ij / 14, j = ij % 14;
    const float* src = t ? adj2 : adj1;
    a[e] = (i == j) ? 1.0f : src[ij];
  }
  __syncthreads();
  if (tid < 28){
    int t = tid / 14, i = tid % 14;
    float s = 0.f;
    for (int j = 0; j < 14; j++) s += a[t*196 + i*14 + j];
    d[tid] = rsqrtf(fmaxf(s, 1.0f));     // clip(sum,1)^-0.5
  }
  __syncthreads();
  for (int e = tid; e < 392; e += 256){
    int t = e / 196, ij = e % 196, i = ij / 14, j = ij % 14;
    adjn[e] = d[t*14+i] * a[e] * d[t*14+j];
  }
}

// ---- fp32 -> bf16 bulk convert -------------------------------------------
__global__ void k_convert_x(const float4* __restrict__ x4, uint2* __restrict__ xb4, int n4){
  int stride = gridDim.x * blockDim.x;
  for (int i = blockIdx.x*blockDim.x + threadIdx.x; i < n4; i += stride){
    float4 f = x4[i];
    uint2 o;
    o.x = (uint32_t)f2bf(f.x) | ((uint32_t)f2bf(f.y) << 16);
    o.y = (uint32_t)f2bf(f.z) | ((uint32_t)f2bf(f.w) << 16);
    xb4[i] = o;
  }
}

// ---- weights: coalesced transpose+convert via 64x64 LDS tiles ------------
// tiles 0..255   : fc_w  [1024][1024] -> bcatT rows 0..1023,    ld 1024
// tiles 256..383 : gcn1_w[1024][512]  -> bcatT rows 1024..1535, ld 1024
// tiles 384..511 : gcn2_w[512][1024]  -> w2T   rows 0..1023,    ld 512
__global__ __launch_bounds__(256)
void k_convert_w(const float* __restrict__ fcw, const float* __restrict__ w1,
                 const float* __restrict__ w2, unsigned short* __restrict__ bcatT,
                 unsigned short* __restrict__ w2T){
  __shared__ float tile[64][65];
  int id = blockIdx.x, tid = threadIdx.x;
  const float* src; unsigned short* dst;
  int lds_src, ldo, row_off, tk, tn;
  if (id < 256){
    src = fcw; dst = bcatT; lds_src = 1024; ldo = 1024; row_off = 0;
    tk = id & 15; tn = id >> 4;
  } else if (id < 384){
    int r = id - 256;
    src = w1; dst = bcatT; lds_src = 512; ldo = 1024; row_off = 1024;
    tk = r & 15; tn = r >> 4;
  } else {
    int r = id - 384;
    src = w2; dst = w2T; lds_src = 1024; ldo = 512; row_off = 0;
    tk = r & 7; tn = r >> 3;
  }
  int c = tid & 63, r0 = tid >> 6;
  #pragma unroll
  for (int i = 0; i < 16; i++){
    int kr = r0 + i*4;
    tile[kr][c] = src[(size_t)(tk*64 + kr)*lds_src + tn*64 + c];
  }
  __syncthreads();
  #pragma unroll
  for (int i = 0; i < 16; i++){
    int nr = r0 + i*4;
    dst[(size_t)(row_off + tn*64 + nr)*ldo + tk*64 + c] = f2bf(tile[c][nr]);
  }
}

// ---- bf16 MFMA GEMM, m97 structure: 128x128 tile, BK=32, B^T weights ------
// 1-D grid, bijective XCD swizzle, bn fast within each XCD chunk (A L2 reuse)
// MODE 1: C[m, n<1024] -> h = leaky(c + fc_b[n]) fp32 ; C[m, n>=1024] -> t1 bf16 [m][n-1024]
// MODE 2: C -> t2 bf16 [m][n]
template<int MODE, int NT>
__global__ __launch_bounds__(256)
void k_gemm_bt(const unsigned short* __restrict__ A, const unsigned short* __restrict__ Bt,
               int K, const float* __restrict__ bias,
               float* __restrict__ h_out, unsigned short* __restrict__ o_bf16){
  __shared__ unsigned short As[4096];  // [128][32]
  __shared__ unsigned short Bs[4096];  // [128][32]
  int tid = threadIdx.x;
  int lane = tid & 63, wave = tid >> 6;
  int wm = wave & 1, wn = wave >> 1;
  // XCD-chunked swizzle: nwg % 8 == 0 for both GEMMs (5376, 7168)
  int cpx = gridDim.x >> 3;
  int orig = blockIdx.x;
  int wgid = (orig & 7) * cpx + (orig >> 3);
  int bn = wgid % NT;
  int bm = wgid / NT;
  const unsigned short* aptr = A  + (size_t)(bm*128 + (tid >> 2))*K + (tid & 3)*8;
  const unsigned short* bptr = Bt + (size_t)(bn*128 + (tid >> 2))*K + (tid & 3)*8;
  unsigned short* asd = &As[tid*8];
  unsigned short* bsd = &Bs[tid*8];
  size_t row64 = (size_t)64 * K;
  int fr = lane & 15, fq = lane >> 4;
  floatx4 acc[4][4] = {};
  for (int k0 = 0; k0 < K; k0 += 32){
    __syncthreads();
    gl2lds16(aptr + k0,         asd);
    gl2lds16(aptr + k0 + row64, asd + 2048);
    gl2lds16(bptr + k0,         bsd);
    gl2lds16(bptr + k0 + row64, bsd + 2048);
    __syncthreads();
    short8 af[4], bq[4];
    #pragma unroll
    for (int i = 0; i < 4; i++)
      af[i] = *(const short8*)&As[(wm*64 + i*16 + fr)*32 + fq*8];
    #pragma unroll
    for (int j = 0; j < 4; j++)
      bq[j] = *(const short8*)&Bs[(wn*64 + j*16 + fr)*32 + fq*8];
    #pragma unroll
    for (int i = 0; i < 4; i++)
      #pragma unroll
      for (int j = 0; j < 4; j++)
        acc[i][j] = __builtin_amdgcn_mfma_f32_16x16x32_bf16(af[i], bq[j], acc[i][j], 0, 0, 0);
  }
  #pragma unroll
  for (int i = 0; i < 4; i++){
    #pragma unroll
    for (int j = 0; j < 4; j++){
      int n  = bn*128 + wn*64 + j*16 + fr;
      int mb = bm*128 + wm*64 + i*16 + fq*4;
      #pragma unroll
      for (int r = 0; r < 4; r++){
        int m = mb + r;
        float c = acc[i][j][r];
        if (MODE == 1){
          if (n < 1024){
            c += bias[n];
            h_out[(size_t)m*1024 + n] = leaky(c);
          } else {
            o_bf16[(size_t)m*512 + (n - 1024)] = f2bf(c);
          }
        } else {
          o_bf16[(size_t)m*1024 + n] = f2bf(c);
        }
      }
    }
  }
}

// ---- corr: per-batch Gram via MFMA (2 batches x 2 K-halves per block) ----
__global__ __launch_bounds__(256)
void k_corr(const float* __restrict__ h, float* __restrict__ corr, float* __restrict__ adjc){
  __shared__ float G[2][16][17];
  __shared__ float Gh[2][16][17];
  __shared__ float C[2][14][15];
  __shared__ float dd[2][16];
  int tid = threadIdx.x;
  int lane = tid & 63, wave = tid >> 6;
  int s = wave >> 1, kh = wave & 1;    // batch slot, K-half
  int b = blockIdx.x*2 + s;
  int r = lane & 15, q = lane >> 4;
  const float* hrow = h + (size_t)(b*14 + r)*1024 + kh*512 + q*8;
  bool valid = r < 14;
  floatx4 acc = {0.f, 0.f, 0.f, 0.f};
  for (int k0 = 0; k0 < 512; k0 += 32){
    short8 f = {0,0,0,0,0,0,0,0};
    if (valid){
      float4 f0 = *(const float4*)(hrow + k0);
      float4 f1 = *(const float4*)(hrow + k0 + 4);
      f[0] = (short)f2bf(f0.x); f[1] = (short)f2bf(f0.y);
      f[2] = (short)f2bf(f0.z); f[3] = (short)f2bf(f0.w);
      f[4] = (short)f2bf(f1.x); f[5] = (short)f2bf(f1.y);
      f[6] = (short)f2bf(f1.z); f[7] = (short)f2bf(f1.w);
    }
    acc = __builtin_amdgcn_mfma_f32_16x16x32_bf16(f, f, acc, 0, 0, 0);  // G = H H^T
  }
  float* gdst = kh ? &Gh[s][0][0] : &G[s][0][0];
  #pragma unroll
  for (int t = 0; t < 4; t++) gdst[(q*4 + t)*17 + r] = acc[t];
  __syncthreads();
  for (int e = tid; e < 512; e += 256){
    int ss = e >> 8, ij = e & 255, i = ij >> 4, j = ij & 15;
    G[ss][i][j] += Gh[ss][i][j];
  }
  __syncthreads();
  if (tid < 28){
    int ss = tid / 14, i = tid % 14;
    dd[ss][i] = rsqrtf(fmaxf(G[ss][i][i], 1e-16f));   // COS_EPS^2
  }
  __syncthreads();
  for (int e = tid; e < 392; e += 256){
    int ss = e / 196, ij = e % 196, i = ij / 14, j = ij % 14;
    float c = (i == j) ? 1.0f : fabsf(G[ss][i][j]) * dd[ss][i] * dd[ss][j];
    C[ss][i][j] = c;
    corr[(size_t)(blockIdx.x*2 + ss)*196 + ij] = c;
  }
  __syncthreads();
  if (tid < 28){
    int ss = tid / 14, i = tid % 14;
    float sum = 0.f;
    #pragma unroll
    for (int j = 0; j < 14; j++) sum += C[ss][i][j];
    dd[ss][i] = rsqrtf(fmaxf(sum, 1.0f));
  }
  __syncthreads();
  for (int e = tid; e < 392; e += 256){
    int ss = e / 196, ij = e % 196, i = ij / 14, j = ij % 14;
    adjc[(size_t)(blockIdx.x*2 + ss)*196 + ij] = C[ss][i][j] * dd[ss][i] * dd[ss][j];
  }
}

// ---- branch1 BN stats: pre = adjn{1,2} @ t1 + b1 ; per-node sum/sumsq ----
__global__ __launch_bounds__(256)
void k_stats1(const unsigned short* __restrict__ t1, const float* __restrict__ adjn,
              const float* __restrict__ b1, float* __restrict__ part){
  __shared__ float adjs[392];
  __shared__ float red[56*4];
  int tid = threadIdx.x, b = blockIdx.x;
  for (int e = tid; e < 392; e += 256) adjs[e] = adjn[e];
  __syncthreads();
  int cc = tid*2;
  const unsigned short* base = t1 + (size_t)b*14*512 + cc;
  float v0[14], v1[14];
  #pragma unroll
  for (int m = 0; m < 14; m++){
    unsigned int u = *(const unsigned int*)(base + m*512);
    v0[m] = bf2f((unsigned short)(u & 0xffffu));
    v1[m] = bf2f((unsigned short)(u >> 16));
  }
  float bias0 = b1[cc], bias1 = b1[cc+1];
  float vals[56];
  #pragma unroll
  for (int br = 0; br < 2; br++){
    #pragma unroll
    for (int n = 0; n < 14; n++){
      float p0 = bias0, p1 = bias1;
      const float* arow = &adjs[br*196 + n*14];
      #pragma unroll
      for (int m = 0; m < 14; m++){ p0 += arow[m]*v0[m]; p1 += arow[m]*v1[m]; }
      vals[(br*14 + n)*2 + 0] = p0 + p1;
      vals[(br*14 + n)*2 + 1] = p0*p0 + p1*p1;
    }
  }
  int lane = tid & 63, wave = tid >> 6;
  #pragma unroll
  for (int i = 0; i < 56; i++){
    float x = vals[i];
    #pragma unroll
    for (int off = 32; off > 0; off >>= 1) x += __shfl_down(x, off, 64);
    if (lane == 0) red[i*4 + wave] = x;
  }
  __syncthreads();
  if (tid < 56)
    part[(size_t)tid*4096 + b] = red[tid*4] + red[tid*4+1] + red[tid*4+2] + red[tid*4+3];
}

// ---- BN finalize: 28 blocks; j = br*14 + n -> scale/shift ----------------
__global__ void k_finalize(const float* __restrict__ part, const float* __restrict__ gA,
                           const float* __restrict__ bA, const float* __restrict__ gB,
                           const float* __restrict__ bB, float inv_count,
                           float* __restrict__ ss){
  int j = blockIdx.x, tid = threadIdx.x;
  const float* ps = part + (size_t)(j*2)*4096;
  const float* pq = ps + 4096;
  float s = 0.f, q = 0.f;
  for (int e = tid; e < 4096; e += 256){ s += ps[e]; q += pq[e]; }
  __shared__ float rs[4], rq[4];
  int lane = tid & 63, wave = tid >> 6;
  #pragma unroll
  for (int off = 32; off > 0; off >>= 1){ s += __shfl_down(s,off,64); q += __shfl_down(q,off,64); }
  if (lane == 0){ rs[wave] = s; rq[wave] = q; }
  __syncthreads();
  if (tid == 0){
    s = rs[0]+rs[1]+rs[2]+rs[3];
    q = rq[0]+rq[1]+rq[2]+rq[3];
    float mu = s * inv_count;
    float var = q * inv_count - mu*mu;
    float rsig = rsqrtf(var + 1e-5f);
    int br = j / 14, n = j % 14;
    float g  = br ? gB[n] : gA[n];
    float be = br ? bB[n] : bA[n];
    float scale = rsig * g;
    ss[j*2]   = scale;
    ss[j*2+1] = be - mu*scale;
  }
}

// ---- branch1 apply: BN+leaky -> outcat bf16 (out rows 0..M1, out3 rows M1..)
__global__ __launch_bounds__(256)
void k_apply1(const unsigned short* __restrict__ t1, const float* __restrict__ adjn,
              const float* __restrict__ b1, const float* __restrict__ ss,
              unsigned short* __restrict__ outcat){
  __shared__ float adjs[392];
  __shared__ float sss[56];
  int tid = threadIdx.x, b = blockIdx.x;
  for (int e = tid; e < 392; e += 256) adjs[e] = adjn[e];
  if (tid < 56) sss[tid] = ss[tid];
  __syncthreads();
  int cc = tid*2;
  const unsigned short* base = t1 + (size_t)b*14*512 + cc;
  float v0[14], v1[14];
  #pragma unroll
  for (int m = 0; m < 14; m++){
    unsigned int u = *(const unsigned int*)(base + m*512);
    v0[m] = bf2f((unsigned short)(u & 0xffffu));
    v1[m] = bf2f((unsigned short)(u >> 16));
  }
  float bias0 = b1[cc], bias1 = b1[cc+1];
  #pragma unroll
  for (int br = 0; br < 2; br++){
    #pragma unroll
    for (int n = 0; n < 14; n++){
      float p0 = bias0, p1 = bias1;
      const float* arow = &adjs[br*196 + n*14];
      #pragma unroll
      for (int m = 0; m < 14; m++){ p0 += arow[m]*v0[m]; p1 += arow[m]*v1[m]; }
      float scale = sss[(br*14+n)*2], shift = sss[(br*14+n)*2+1];
      float y0 = leaky(p0*scale + shift);
      float y1 = leaky(p1*scale + shift);
      size_t row = (size_t)br*M1 + (size_t)b*14 + n;
      *(unsigned int*)(outcat + row*512 + cc) =
          (uint32_t)f2bf(y0) | ((uint32_t)f2bf(y1) << 16);
    }
  }
}

// ---- branch2 BN stats: pre = adjc[b] @ t2{half} + b2 ---------------------
__global__ __launch_bounds__(512)
void k_stats2(const unsigned short* __restrict__ t2, const float* __restrict__ adjc,
              const float* __restrict__ b2, float* __restrict__ part){
  __shared__ float adjs[196];
  __shared__ float red[28*8];
  int tid = threadIdx.x, b = blockIdx.x;
  for (int e = tid; e < 196; e += 512) adjs[e] = adjc[(size_t)b*196 + e];
  __syncthreads();
  int cc = tid*2;
  float bias0 = b2[cc], bias1 = b2[cc+1];
  int lane = tid & 63, wave = tid >> 6;
  for (int half = 0; half < 2; half++){
    const unsigned short* base = t2 + ((size_t)half*M1 + (size_t)b*14)*1024 + cc;
    float v0[14], v1[14];
    #pragma unroll
    for (int m = 0; m < 14; m++){
      unsigned int u = *(const unsigned int*)(base + (size_t)m*1024);
      v0[m] = bf2f((unsigned short)(u & 0xffffu));
      v1[m] = bf2f((unsigned short)(u >> 16));
    }
    float vals[28];
    #pragma unroll
    for (int n = 0; n < 14; n++){
      float p0 = bias0, p1 = bias1;
      const float* arow = &adjs[n*14];
      #pragma unroll
      for (int m = 0; m < 14; m++){ p0 += arow[m]*v0[m]; p1 += arow[m]*v1[m]; }
      vals[n*2]   = p0 + p1;
      vals[n*2+1] = p0*p0 + p1*p1;
    }
    #pragma unroll
    for (int i = 0; i < 28; i++){
      float x = vals[i];
      #pragma unroll
      for (int off = 32; off > 0; off >>= 1) x += __shfl_down(x, off, 64);
      if (lane == 0) red[i*8 + wave] = x;
    }
    __syncthreads();
    if (tid < 28){
      float x = 0.f;
      #pragma unroll
      for (int w = 0; w < 8; w++) x += red[tid*8 + w];
      part[(size_t)(half*28 + tid)*4096 + b] = x;
    }
    __syncthreads();
  }
}

// ---- branch2 apply: out2 + out4 -> d_out fp32 -----------------------------
__global__ __launch_bounds__(512)
void k_apply2(const unsigned short* __restrict__ t2, const float* __restrict__ adjc,
              const float* __restrict__ b2, const float* __restrict__ ss,
              float* __restrict__ out){
  __shared__ float adjs[196];
  __shared__ float sss[56];
  int tid = threadIdx.x, b = blockIdx.x;
  for (int e = tid; e < 196; e += 512) adjs[e] = adjc[(size_t)b*196 + e];
  if (tid < 56) sss[tid] = ss[tid];
  __syncthreads();
  int cc = tid*2;
  float bias0 = b2[cc], bias1 = b2[cc+1];
  const unsigned short* base2 = t2 + ((size_t)b*14)*1024 + cc;
  const unsigned short* base4 = t2 + ((size_t)M1 + (size_t)b*14)*1024 + cc;
  float v20[14], v21[14], v40[14], v41[14];
  #pragma unroll
  for (int m = 0; m < 14; m++){
    unsigned int u = *(const unsigned int*)(base2 + (size_t)m*1024);
    v20[m] = bf2f((unsigned short)(u & 0xffffu)); v21[m] = bf2f((unsigned short)(u >> 16));
    unsigned int w = *(const unsigned int*)(base4 + (size_t)m*1024);
    v40[m] = bf2f((unsigned short)(w & 0xffffu)); v41[m] = bf2f((unsigned short)(w >> 16));
  }
  #pragma unroll
  for (int n = 0; n < 14; n++){
    float p20 = bias0, p21 = bias1, p40 = bias0, p41 = bias1;
    const float* arow = &adjs[n*14];
    #pragma unroll
    for (int m = 0; m < 14; m++){
      float a = arow[m];
      p20 += a*v20[m]; p21 += a*v21[m]; p40 += a*v40[m]; p41 += a*v41[m];
    }
    float s2 = sss[n*2],      h2 = sss[n*2+1];
    float s4 = sss[28 + n*2], h4 = sss[28 + n*2+1];
    float2 o;
    o.x = leaky(p20*s2 + h2) + leaky(p40*s4 + h4);
    o.y = leaky(p21*s2 + h2) + leaky(p41*s4 + h4);
    *(float2*)(out + ((size_t)b*14 + n)*1024 + cc) = o;
  }
}

extern "C" void kernel_launch(void* const* d_in, const int* in_sizes, int n_in,
                              void* d_out, int out_size, void* d_ws, size_t ws_size,
                              hipStream_t stream){
  const float* x      = (const float*)d_in[0];
  const float* adj1   = (const float*)d_in[1];
  const float* adj2   = (const float*)d_in[2];
  const float* fc_w   = (const float*)d_in[3];
  const float* fc_b   = (const float*)d_in[4];
  const float* g1w    = (const float*)d_in[5];
  const float* g1b    = (const float*)d_in[6];
  const float* g2w    = (const float*)d_in[7];
  const float* g2b    = (const float*)d_in[8];
  const float* gamma1 = (const float*)d_in[9];
  const float* beta1  = (const float*)d_in[10];
  const float* gamma2 = (const float*)d_in[11];
  const float* beta2  = (const float*)d_in[12];
  const float* gamma3 = (const float*)d_in[13];
  const float* beta3  = (const float*)d_in[14];

  float* out_main = (float*)d_out;                       // out2+out4 [57344][1024]
  float* out_corr = out_main + (size_t)M1*1024;          // corr [4096][196]
  float* out_h    = out_corr + (size_t)B_SZ*196;         // h [57344][1024]

  char* ws = (char*)d_ws;
  unsigned short* xb     = (unsigned short*)(ws + OFF_XB);
  unsigned short* outcat = (unsigned short*)(ws + OFF_XB);   // alias: x dead after gemm1
  unsigned short* bcatT  = (unsigned short*)(ws + OFF_BCAT);
  unsigned short* w2T    = (unsigned short*)(ws + OFF_W2T);
  unsigned short* t1     = (unsigned short*)(ws + OFF_T);
  unsigned short* t2     = (unsigned short*)(ws + OFF_T);    // alias: t1 dead after apply1
  float* adjn  = (float*)(ws + OFF_ADJN);
  float* adjc  = (float*)(ws + OFF_ADJC);
  float* part1 = (float*)(ws + OFF_PART1);
  float* part2 = (float*)(ws + OFF_PART2);
  float* ss1   = (float*)(ws + OFF_SS1);
  float* ss2   = (float*)(ws + OFF_SS2);

  k_prep_adj<<<1, 256, 0, stream>>>(adj1, adj2, adjn);
  k_convert_x<<<8192, 256, 0, stream>>>((const float4*)x, (uint2*)xb, 14680064);
  k_convert_w<<<512, 256, 0, stream>>>(fc_w, g1w, g2w, bcatT, w2T);
  // GEMM1: x @ [fc_w | gcn1_w]  -> h (leaky, fp32) and t1 (bf16)
  // grid = 448*12 = 5376 (M-tiles x N-tiles), 1-D with XCD swizzle, bn fast
  k_gemm_bt<1, 12><<<5376, 256, 0, stream>>>(xb, bcatT, 1024, fc_b, out_h, t1);
  k_corr<<<2048, 256, 0, stream>>>(out_h, out_corr, adjc);
  k_stats1<<<4096, 256, 0, stream>>>(t1, adjn, g1b, part1);
  k_finalize<<<28, 256, 0, stream>>>(part1, gamma1, beta1, gamma3, beta3,
                                     1.0f/(4096.0f*512.0f), ss1);
  k_apply1<<<4096, 256, 0, stream>>>(t1, adjn, g1b, ss1, outcat);
  // GEMM2: [out ; out3] @ gcn2_w -> t2 (bf16); grid = 896*8 = 7168
  k_gemm_bt<2, 8><<<7168, 256, 0, stream>>>(outcat, w2T, 512, nullptr, nullptr, t2);
  k_stats2<<<4096, 512, 0, stream>>>(t2, adjc, g2b, part2);
  k_finalize<<<28, 256, 0, stream>>>(part2, gamma2, beta2, gamma2, beta2,
                                     1.0f/(4096.0f*1024.0f), ss2);
  k_apply2<<<4096, 512, 0, stream>>>(t2, adjc, g2b, ss2, out_main);
}